// Round 1
// baseline (120.544 us; speedup 1.0000x reference)
//
#include <hip/hip_runtime.h>

#define SQ1_2 0.70710678118654752440f

// g(x) = sign(x) * log1p(|x|)
__device__ __forceinline__ float g_feat(float x) {
    return copysignf(__logf(1.0f + fabsf(x)), x);
}

// Real 8-point DFT. Input r[0..7]; output packed:
// o[0]=F0 (real), o[1]=F4 (real), o[2..3]=F1 (re,im), o[4..5]=F2, o[6..7]=F3.
// F[5..7] = conj(F[3..1]) implied.
__device__ __forceinline__ void rfft8(const float r[8], float o[8]) {
    float s0 = r[0] + r[4], d0 = r[0] - r[4];
    float s1 = r[1] + r[5], d1 = r[1] - r[5];
    float s2 = r[2] + r[6], d2 = r[2] - r[6];
    float s3 = r[3] + r[7], d3 = r[3] - r[7];
    float ss02 = s0 + s2, sd02 = s0 - s2;
    float ss13 = s1 + s3, sd13 = s1 - s3;
    float t1 = SQ1_2 * (d1 - d3);
    float t2 = SQ1_2 * (d1 + d3);
    o[0] = ss02 + ss13;       // F0
    o[1] = ss02 - ss13;       // F4
    o[2] = d0 + t1;           // F1r
    o[3] = -(d2 + t2);        // F1i
    o[4] = sd02;              // F2r
    o[5] = -sd13;             // F2i
    o[6] = d0 - t1;           // F3r
    o[7] = d2 - t2;           // F3i
}

// Complex 8-point DFT (DIT radix-2): inputs xr/xi[8], outputs Fr/Fi[8].
__device__ __forceinline__ void cfft8(const float xr[8], const float xi[8],
                                      float Fr[8], float Fi[8]) {
    float s0r = xr[0] + xr[4], s0i = xi[0] + xi[4], d0r = xr[0] - xr[4], d0i = xi[0] - xi[4];
    float s1r = xr[1] + xr[5], s1i = xi[1] + xi[5], d1r = xr[1] - xr[5], d1i = xi[1] - xi[5];
    float s2r = xr[2] + xr[6], s2i = xi[2] + xi[6], d2r = xr[2] - xr[6], d2i = xi[2] - xi[6];
    float s3r = xr[3] + xr[7], s3i = xi[3] + xi[7], d3r = xr[3] - xr[7], d3i = xi[3] - xi[7];
    // even half: DFT4 of s
    float ss0r = s0r + s2r, ss0i = s0i + s2i, sd0r = s0r - s2r, sd0i = s0i - s2i;
    float ss1r = s1r + s3r, ss1i = s1i + s3i, sd1r = s1r - s3r, sd1i = s1i - s3i;
    Fr[0] = ss0r + ss1r; Fi[0] = ss0i + ss1i;
    Fr[4] = ss0r - ss1r; Fi[4] = ss0i - ss1i;
    Fr[2] = sd0r + sd1i; Fi[2] = sd0i - sd1r;   // sd0 - i*sd1
    Fr[6] = sd0r - sd1i; Fi[6] = sd0i + sd1r;   // sd0 + i*sd1
    // odd half: twiddle then DFT4
    float t1r = SQ1_2 * (d1r + d1i), t1i = SQ1_2 * (d1i - d1r);   // d1 * e^{-i pi/4}
    float t2r = d2i,                 t2i = -d2r;                  // d2 * (-i)
    float t3r = SQ1_2 * (d3i - d3r), t3i = -SQ1_2 * (d3r + d3i);  // d3 * e^{-i 3pi/4}
    float ts0r = d0r + t2r, ts0i = d0i + t2i, td0r = d0r - t2r, td0i = d0i - t2i;
    float ts1r = t1r + t3r, ts1i = t1i + t3i, td1r = t1r - t3r, td1i = t1i - t3i;
    Fr[1] = ts0r + ts1r; Fi[1] = ts0i + ts1i;
    Fr[5] = ts0r - ts1r; Fi[5] = ts0i - ts1i;
    Fr[3] = td0r + td1i; Fi[3] = td0i - td1r;
    Fr[7] = td0r - td1i; Fi[7] = td0i + td1r;
}

// Load 8x8 patch (scaled by 1/8 for ortho norm) and run stage-1 row FFTs.
// v[m*8 + 0..7] = packed rfft8 of row m.
__device__ __forceinline__ void stage1(const float* __restrict__ src, long base,
                                       float v[64]) {
    #pragma unroll
    for (int m = 0; m < 8; ++m) {
        const float4* p = reinterpret_cast<const float4*>(src + base + (long)m * 512);
        float4 a = p[0];
        float4 b = p[1];
        float r[8] = {a.x * 0.125f, a.y * 0.125f, a.z * 0.125f, a.w * 0.125f,
                      b.x * 0.125f, b.y * 0.125f, b.z * 0.125f, b.w * 0.125f};
        rfft8(r, &v[m * 8]);
    }
}

// Stage 2 for the input tensor: produce 64 feature scalars (g applied).
// f[0..7]   : col l=0 packed (idx0,1 -> weight1; 2..7 -> weight2)
// f[8..15]  : col l=4 packed (same weights)
// f[16+16*l + k], f[16+16*l+8 + k] : cols l=1..3, Fr/Fi (all weight2)
__device__ __forceinline__ void stage2_feats(const float v[64], float f[64]) {
    #pragma unroll
    for (int j = 0; j < 2; ++j) {
        float c[8], o[8];
        #pragma unroll
        for (int m = 0; m < 8; ++m) c[m] = v[m * 8 + j];
        rfft8(c, o);
        #pragma unroll
        for (int k = 0; k < 8; ++k) f[j * 8 + k] = g_feat(o[k]);
    }
    #pragma unroll
    for (int l = 0; l < 3; ++l) {
        float cr[8], ci[8], Fr[8], Fi[8];
        #pragma unroll
        for (int m = 0; m < 8; ++m) {
            cr[m] = v[m * 8 + 2 + 2 * l];
            ci[m] = v[m * 8 + 3 + 2 * l];
        }
        cfft8(cr, ci, Fr, Fi);
        #pragma unroll
        for (int k = 0; k < 8; ++k) {
            f[16 + l * 16 + k]     = g_feat(Fr[k]);
            f[16 + l * 16 + 8 + k] = g_feat(Fi[k]);
        }
    }
}

__global__ __launch_bounds__(256) void patchfft_loss_kernel(
        const float* __restrict__ in, const float* __restrict__ tgt,
        float* __restrict__ out) {
    int p = blockIdx.x * 256 + threadIdx.x;      // patch id, exactly 196608 threads
    int pw = p & 63;
    int ph = (p >> 6) & 63;
    int bc = p >> 12;                            // fused batch*channel (0..47)
    long base = (long)bc * 262144 + ph * 4096 + pw * 8;

    float a[64];
    stage1(in, base, a);
    float f[64];
    stage2_feats(a, f);

    stage1(tgt, base, a);   // reuse registers for target stage-1

    float acc1 = 0.0f, acc2 = 0.0f;
    // target stage-2, accumulate against input features group-by-group
    #pragma unroll
    for (int j = 0; j < 2; ++j) {
        float c[8], o[8];
        #pragma unroll
        for (int m = 0; m < 8; ++m) c[m] = a[m * 8 + j];
        rfft8(c, o);
        {
            float d0 = f[j * 8 + 0] - g_feat(o[0]); acc1 += d0 * d0;  // k=0, weight 1
            float d1 = f[j * 8 + 1] - g_feat(o[1]); acc1 += d1 * d1;  // k=4, weight 1
        }
        #pragma unroll
        for (int k = 2; k < 8; ++k) {
            float d = f[j * 8 + k] - g_feat(o[k]); acc2 += d * d;     // k=1..3, weight 2
        }
    }
    #pragma unroll
    for (int l = 0; l < 3; ++l) {
        float cr[8], ci[8], Fr[8], Fi[8];
        #pragma unroll
        for (int m = 0; m < 8; ++m) {
            cr[m] = a[m * 8 + 2 + 2 * l];
            ci[m] = a[m * 8 + 3 + 2 * l];
        }
        cfft8(cr, ci, Fr, Fi);
        #pragma unroll
        for (int k = 0; k < 8; ++k) {
            float d = f[16 + l * 16 + k]     - g_feat(Fr[k]); acc2 += d * d;
            float e = f[16 + l * 16 + 8 + k] - g_feat(Fi[k]); acc2 += e * e;
        }
    }
    float loss = acc1 + 2.0f * acc2;

    // wave (64-lane) shuffle reduce, then block reduce, then one atomic/block
    #pragma unroll
    for (int off = 32; off > 0; off >>= 1) loss += __shfl_down(loss, off, 64);
    __shared__ float wsum[4];
    int lane = threadIdx.x & 63;
    int wid  = threadIdx.x >> 6;
    if (lane == 0) wsum[wid] = loss;
    __syncthreads();
    if (threadIdx.x == 0) {
        float s = wsum[0] + wsum[1] + wsum[2] + wsum[3];
        atomicAdd(out, s * (1.0f / 12582912.0f));
    }
}

extern "C" void kernel_launch(void* const* d_in, const int* in_sizes, int n_in,
                              void* d_out, int out_size, void* d_ws, size_t ws_size,
                              hipStream_t stream) {
    const float* in  = (const float*)d_in[0];
    const float* tgt = (const float*)d_in[1];
    float* out = (float*)d_out;
    (void)in_sizes; (void)n_in; (void)d_ws; (void)ws_size; (void)out_size;

    hipMemsetAsync(out, 0, sizeof(float), stream);   // d_out is poisoned 0xAA pre-launch
    // 196608 patches, one thread each
    patchfft_loss_kernel<<<768, 256, 0, stream>>>(in, tgt, out);
}